// Round 10
// baseline (13604.926 us; speedup 1.0000x reference)
//
#include <hip/hip_runtime.h>

#define BB 256
#define NN 512
#define DD 128
#define HH 8

static constexpr float NEGC = -1e9f;
static constexpr float INV_SQRT_D = 0.08838834764831845f; // 1/sqrt(128)

__device__ __forceinline__ float dot4(float4 a, float4 b) {
    return a.x * b.x + a.y * b.y + a.z * b.z + a.w * b.w;
}

// ---------------- precompute: fixed_ctx = mean_n(E) @ W_fixed ----------------
__global__ __launch_bounds__(128)
void precompute_fc(const float* __restrict__ E, const float* __restrict__ Wf,
                   float* __restrict__ fc) {
    int b = blockIdx.x, d = threadIdx.x;
    __shared__ float ge[DD];
    const float* Eb = E + (size_t)b * NN * DD;
    float s = 0.f;
    for (int n = 0; n < NN; ++n) s += Eb[n * DD + d];
    ge[d] = s * (1.0f / 512.0f);
    __syncthreads();
    float o = 0.f;
    for (int k = 0; k < DD; ++k) o += ge[k] * Wf[k * DD + d];
    fc[b * DD + d] = o;
}

// ---- precompute: WkT[k][d] = W_node[d][k] (k<128);  W_og = W_out @ Wl^T ----
__global__ __launch_bounds__(128)
void precompute_w(const float* __restrict__ Wn, const float* __restrict__ Wout,
                  float* __restrict__ Wog, float* __restrict__ WkT) {
    int k = blockIdx.x, d = threadIdx.x;
    WkT[k * DD + d] = Wn[d * 384 + k];
    float s = 0.f;
    for (int e = 0; e < DD; ++e) s += Wout[k * DD + e] * Wn[d * 384 + 256 + e];
    Wog[k * DD + d] = s;
}

// ---------------------------- main decoder ----------------------------------
// 1024 threads / 16 waves (48% occupancy; empirical VGPR budget 65536/1024=64,
// working set <=~45 -> resident). E-lo in LDS (swizzled), E-hi from global.
// Broadcasts via same-address LDS reads. No persistent E regs, no s_load.
struct SMy {
    float EA[NN * 64];    // 131072  E-lo, row n quad q at (q^(n&15))
    float P[HH][520];     // 16640   attn weights; aliased pa[4][8][128] partials
    float qt[HH][DD];     // 4096
    float eb[HH][DD];     // 4096
    float part[HH][DD];   // 4096    phase partials; lgp[512] alias during logits
    float qarr[DD];       // q, later g~
    float fcs[DD];
    float hc[DD];
    float l[HH];
    float Mh[HH];
    float redf[16];
    float stat[2];
    int   cur;
    float rbv;
};

__global__ __launch_bounds__(1024)
void decoder(const float* __restrict__ E, const float* __restrict__ Ws,
             const float* __restrict__ Wn, const float* __restrict__ fc,
             const float* __restrict__ Wog, const float* __restrict__ WkT,
             float* __restrict__ out_logp, float* __restrict__ out_seq, int T) {
    __shared__ SMy sm;
    const int b = blockIdx.x, tid = threadIdx.x;
    const int lane = tid & 63, wv = tid >> 6;
    const int g8 = tid >> 7, d128 = tid & 127;     // (group/head, dim)
    const int n2 = tid >> 1, hf = tid & 1;         // (row, half) for compat/logits
    const int rg = tid >> 7, dd = tid & 127;       // (row-group, dim) for e-bar
    const float* Eg = E + (size_t)b * NN * DD;
    const float4* Ef4 = (const float4*)Eg;

    // ---- init: EA (E-lo swizzled), fcs, rbv, cur ----
    #pragma unroll
    for (int i = 0; i < 8; ++i) {
        int f = i * 1024 + tid;
        int nn = f >> 4, c = f & 15;
        if (c < 16 && (f & 8) == 0) {}             // (no-op; keep indices simple)
        if ((f & 15) < 16) {
            int cq = f & 15;
            if (cq < 16 && (cq < 16)) {
                if (cq < 16 && nn < NN && cq < 16) {
                    if (cq < 16) {
                        if (cq < 16 && (cq < 16)) {}
                    }
                }
            }
        }
        // E row nn has 32 float4 quads; quads 0..15 are the lo half.
        int cq = f & 15;
        *(float4*)&sm.EA[nn * 64 + ((cq ^ (nn & 15)) << 2)] = Ef4[nn * 32 + cq];
    }
    bool vis = false;                              // visited flag for row n2
    if (tid < DD) sm.fcs[tid] = fc[b * DD + tid];
    if (tid == 0) sm.cur = 0;
    {   // Rb = max_n ||E[n]|| : thread (n2,hf) does half a row
        float s = 0.f;
        #pragma unroll
        for (int i = 0; i < 16; ++i) {
            float4 v = Ef4[n2 * 32 + hf * 16 + i];
            s += dot4(v, v);
        }
        s += __shfl_xor(s, 1);
        for (int o = 2; o < 64; o <<= 1) s = fmaxf(s, __shfl_xor(s, o));
        if (lane == 0) sm.redf[wv] = s;
    }
    __syncthreads();
    if (tid == 0) {
        float m = sm.redf[0];
        for (int i = 1; i < 16; ++i) m = fmaxf(m, sm.redf[i]);
        sm.rbv = sqrtf(m);
    }
    __syncthreads();

    float* const pa  = &sm.P[0][0];                // partial alias [4][8][128]
    float* const lgp = &sm.part[0][0];             // logits alias  [512]

    for (int t = 0; t < T; ++t) {
        const int cu = sm.cur, cm = cu & 15;
        // ---- phase 0: q = fc + E[cur]@Ws + frac*Ws_last (8 k-groups of 16) ----
        {
            float s = 0.f;
            const float* Wsg = Ws + d128;
            #pragma unroll
            for (int j = 0; j < 16; ++j) {
                int k = g8 * 16 + j;
                float ek = (k < 64)
                    ? sm.EA[cu * 64 + (((k >> 2) ^ cm) << 2) + (k & 3)]
                    : Eg[cu * DD + k];
                s += ek * Wsg[k * DD];
            }
            if (g8 == 7) s += ((float)t / (float)T) * Wsg[DD * DD];
            sm.part[g8][d128] = s;
        }
        __syncthreads();                                               // B1
        if (tid < DD) {
            float s = sm.fcs[tid];
            #pragma unroll
            for (int g = 0; g < 8; ++g) s += sm.part[g][tid];
            sm.qarr[tid] = s;
        }
        __syncthreads();                                               // B2
        // ---- qt[h][d] (0.25 folded) + wave norm partials ----
        {
            float a = 0.f;
            const float* WA = WkT + (g8 * 16) * DD + d128;
            #pragma unroll
            for (int j = 0; j < 16; ++j) a += sm.qarr[g8 * 16 + j] * WA[j * DD];
            a *= 0.25f;
            sm.qt[g8][d128] = a;
            float sa = a * a;
            for (int o = 1; o < 64; o <<= 1) sa += __shfl_xor(sa, o);
            if (lane == 0) sm.redf[wv] = sa;
        }
        __syncthreads();                                               // B3
        if (tid < 8)
            sm.Mh[tid] = sqrtf(sm.redf[2 * tid] + sm.redf[2 * tid + 1]) * sm.rbv;
        __syncthreads();                                               // B4

        // ---- compat: thread (n2,hf) does its half; shfl(1) combine; exp -> P ----
        {
            float a0 = 0.f, a1 = 0.f, a2 = 0.f, a3 = 0.f,
                  a4 = 0.f, a5 = 0.f, a6 = 0.f, a7 = 0.f;
            const int nm = n2 & 15;
            #pragma unroll
            for (int q = 0; q < 16; ++q) {
                float4 ev = (hf == 0)
                    ? *(const float4*)&sm.EA[n2 * 64 + ((q ^ nm) << 2)]
                    : Ef4[n2 * 32 + 16 + q];
                const int qb = hf * 64 + q * 4;
                a0 += dot4(*(const float4*)&sm.qt[0][qb], ev);
                a1 += dot4(*(const float4*)&sm.qt[1][qb], ev);
                a2 += dot4(*(const float4*)&sm.qt[2][qb], ev);
                a3 += dot4(*(const float4*)&sm.qt[3][qb], ev);
                a4 += dot4(*(const float4*)&sm.qt[4][qb], ev);
                a5 += dot4(*(const float4*)&sm.qt[5][qb], ev);
                a6 += dot4(*(const float4*)&sm.qt[6][qb], ev);
                a7 += dot4(*(const float4*)&sm.qt[7][qb], ev);
            }
            a0 += __shfl_xor(a0, 1); a1 += __shfl_xor(a1, 1);
            a2 += __shfl_xor(a2, 1); a3 += __shfl_xor(a3, 1);
            a4 += __shfl_xor(a4, 1); a5 += __shfl_xor(a5, 1);
            a6 += __shfl_xor(a6, 1); a7 += __shfl_xor(a7, 1);
            if (hf == 0) {
                sm.P[0][n2] = vis ? 0.f : expf(a0 - sm.Mh[0]);
                sm.P[1][n2] = vis ? 0.f : expf(a1 - sm.Mh[1]);
                sm.P[2][n2] = vis ? 0.f : expf(a2 - sm.Mh[2]);
                sm.P[3][n2] = vis ? 0.f : expf(a3 - sm.Mh[3]);
                sm.P[4][n2] = vis ? 0.f : expf(a4 - sm.Mh[4]);
                sm.P[5][n2] = vis ? 0.f : expf(a5 - sm.Mh[5]);
                sm.P[6][n2] = vis ? 0.f : expf(a6 - sm.Mh[6]);
                sm.P[7][n2] = vis ? 0.f : expf(a7 - sm.Mh[7]);
            }
        }
        __syncthreads();                                               // B5

        // ---- l[h] (waves 0-7) runs concurrently with e-bar accumulation ----
        if (wv < 8) {
            const int h = wv;
            float sl = 0.f;
            #pragma unroll
            for (int i = 0; i < 8; ++i) sl += sm.P[h][lane + i * 64];
            for (int o = 1; o < 64; o <<= 1) sl += __shfl_xor(sl, o);
            if (lane == 0) sm.l[h] = sl;
        }
        // ---- e-bar accum: thread (rg,dd) over 64 rows; P via float4 broadcast ----
        float c0 = 0.f, c1 = 0.f, c2 = 0.f, c3 = 0.f,
              c4 = 0.f, c5 = 0.f, c6 = 0.f, c7 = 0.f;
        {
            const int r0 = rg * 64;
            const int dq = dd >> 2, dc = dd & 3;
            #pragma unroll 4
            for (int g = 0; g < 16; ++g) {
                const int r = r0 + g * 4;
                float ev0, ev1, ev2, ev3;
                if (dd < 64) {
                    ev0 = sm.EA[(r + 0) * 64 + ((dq ^ ((r + 0) & 15)) << 2) + dc];
                    ev1 = sm.EA[(r + 1) * 64 + ((dq ^ ((r + 1) & 15)) << 2) + dc];
                    ev2 = sm.EA[(r + 2) * 64 + ((dq ^ ((r + 2) & 15)) << 2) + dc];
                    ev3 = sm.EA[(r + 3) * 64 + ((dq ^ ((r + 3) & 15)) << 2) + dc];
                } else {
                    ev0 = Eg[(r + 0) * DD + dd];
                    ev1 = Eg[(r + 1) * DD + dd];
                    ev2 = Eg[(r + 2) * DD + dd];
                    ev3 = Eg[(r + 3) * DD + dd];
                }
                #pragma unroll
                for (int h = 0; h < 8; h += 2) {
                    float4 pA = *(const float4*)&sm.P[h][r];
                    float4 pB = *(const float4*)&sm.P[h + 1][r];
                    float* cA = (h == 0) ? &c0 : (h == 2) ? &c2 : (h == 4) ? &c4 : &c6;
                    float* cB = (h == 0) ? &c1 : (h == 2) ? &c3 : (h == 4) ? &c5 : &c7;
                    *cA += pA.x * ev0 + pA.y * ev1 + pA.z * ev2 + pA.w * ev3;
                    *cB += pB.x * ev0 + pB.y * ev1 + pB.z * ev2 + pB.w * ev3;
                }
            }
        }
        __syncthreads();                                               // B6 (P dead)
        if (rg < 4) {       // stage A: write partial slots into P-alias
            float* d = pa + (size_t)rg * 1024 + dd;
            d[0 * 128] = c0; d[1 * 128] = c1; d[2 * 128] = c2; d[3 * 128] = c3;
            d[4 * 128] = c4; d[5 * 128] = c5; d[6 * 128] = c6; d[7 * 128] = c7;
        }
        __syncthreads();                                               // B7
        if (rg >= 4) {      // stage B: add into slot rg-4
            float* d = pa + (size_t)(rg - 4) * 1024 + dd;
            d[0 * 128] += c0; d[1 * 128] += c1; d[2 * 128] += c2; d[3 * 128] += c3;
            d[4 * 128] += c4; d[5 * 128] += c5; d[6 * 128] += c6; d[7 * 128] += c7;
        }
        __syncthreads();                                               // B8
        {   // combine 4 slots -> eb[h][d] normalized
            float a = pa[0 * 1024 + g8 * 128 + d128] + pa[1 * 1024 + g8 * 128 + d128]
                    + pa[2 * 1024 + g8 * 128 + d128] + pa[3 * 1024 + g8 * 128 + d128];
            sm.eb[g8][d128] = a * (1.0f / sm.l[g8]);
        }
        __syncthreads();                                               // B9

        // ---- phase 2: hc = eb @ Wv ; g~ = hc @ W_og ----
        {
            float s = 0.f;
            const int hh = d128 >> 4;
            const float* Wvp = Wn + 128 + d128;
            #pragma unroll
            for (int j = 0; j < 16; ++j) {
                int d = g8 * 16 + j;
                s += sm.eb[hh][d] * Wvp[d * 384];
            }
            sm.part[g8][d128] = s;
        }
        __syncthreads();                                               // B10
        if (tid < DD) {
            float s = 0.f;
            #pragma unroll
            for (int g = 0; g < 8; ++g) s += sm.part[g][tid];
            sm.hc[tid] = s;
        }
        __syncthreads();                                               // B11
        {
            float s = 0.f;
            #pragma unroll
            for (int j = 0; j < 16; ++j) {
                int k = g8 * 16 + j;
                s += sm.hc[k] * Wog[k * DD + d128];
            }
            sm.part[g8][d128] = s;
        }
        __syncthreads();                                               // B12
        if (tid < DD) {
            float s = 0.f;
            #pragma unroll
            for (int g = 0; g < 8; ++g) s += sm.part[g][tid];
            sm.qarr[tid] = s * INV_SQRT_D;        // qarr reused as g~
        }
        __syncthreads();                                               // B13

        // ---- logits: thread (n2,hf) half-dot; shfl(1); tanh -> lgp (part alias) ----
        {
            float s = 0.f;
            const int nm = n2 & 15;
            #pragma unroll
            for (int q = 0; q < 16; ++q) {
                float4 ev = (hf == 0)
                    ? *(const float4*)&sm.EA[n2 * 64 + ((q ^ nm) << 2)]
                    : Ef4[n2 * 32 + 16 + q];
                s += dot4(*(const float4*)&sm.qarr[hf * 64 + q * 4], ev);
            }
            s += __shfl_xor(s, 1);
            float lg = vis ? NEGC : 10.0f * tanhf(s);
            if (hf == 0) lgp[n2] = lg;
        }
        __syncthreads();                                               // B14

        // ---- stats + argmax in wave 0 only ----
        if (wv == 0) {
            float x0 = lgp[lane],       x1 = lgp[lane + 64],
                  x2 = lgp[lane + 128], x3 = lgp[lane + 192],
                  x4 = lgp[lane + 256], x5 = lgp[lane + 320],
                  x6 = lgp[lane + 384], x7 = lgp[lane + 448];
            float m = fmaxf(fmaxf(fmaxf(x0, x1), fmaxf(x2, x3)),
                            fmaxf(fmaxf(x4, x5), fmaxf(x6, x7)));
            for (int o = 1; o < 64; o <<= 1) m = fmaxf(m, __shfl_xor(m, o));
            float ssum = expf(x0 - m) + expf(x1 - m) + expf(x2 - m) + expf(x3 - m)
                       + expf(x4 - m) + expf(x5 - m) + expf(x6 - m) + expf(x7 - m);
            for (int o = 1; o < 64; o <<= 1) ssum += __shfl_xor(ssum, o);
            float lse = logf(ssum);
            // argmax over lp (= x - m - lse, the stored values), lowest index wins
            float bv = (x0 - m) - lse; int bi = lane;
#define AMX(xi, ii) { float v_ = ((xi) - m) - lse; int i_ = (ii);           \
            if (v_ > bv) { bv = v_; bi = i_; } }
            AMX(x1, lane + 64)  AMX(x2, lane + 128) AMX(x3, lane + 192)
            AMX(x4, lane + 256) AMX(x5, lane + 320) AMX(x6, lane + 384)
            AMX(x7, lane + 448)
#undef AMX
            for (int o = 1; o < 64; o <<= 1) {
                float ov = __shfl_xor(bv, o);
                int   oi = __shfl_xor(bi, o);
                if (ov > bv || (ov == bv && oi < bi)) { bv = ov; bi = oi; }
            }
            if (lane == 0) {
                sm.stat[0] = m;
                sm.stat[1] = lse;
                sm.cur = bi;
                out_seq[(size_t)b * T + t] = (float)bi;
            }
        }
        __syncthreads();                                               // B15
        // ---- store log_p; update visited ----
        if (tid < NN) {
            float lp = (lgp[tid] - sm.stat[0]) - sm.stat[1];
            out_logp[((size_t)b * T + t) * NN + tid] = lp;
        }
        if (n2 == sm.cur) vis = true;
        __syncthreads();                                               // B16
    }
}

// ------------------------------- launcher -----------------------------------
extern "C" void kernel_launch(void* const* d_in, const int* in_sizes, int n_in,
                              void* d_out, int out_size, void* d_ws, size_t ws_size,
                              hipStream_t stream) {
    const float* E    = (const float*)d_in[0];   // [B,N,D]
    const float* Wn   = (const float*)d_in[1];   // [D,3D]
    const float* Wf   = (const float*)d_in[2];   // [D,D]
    const float* Ws   = (const float*)d_in[3];   // [D+1,D]
    const float* Wout = (const float*)d_in[4];   // [D,D]
    float* out = (float*)d_out;

    const int T = out_size / (BB * (NN + 1));    // = num_steps (64)

    float* fc  = (float*)d_ws;                   // [B,D]
    float* Wog = fc + BB * DD;                   // [128,128]
    float* WkT = Wog + DD * DD;                  // [128,128]

    precompute_fc<<<BB, 128, 0, stream>>>(E, Wf, fc);
    precompute_w<<<DD, 128, 0, stream>>>(Wn, Wout, Wog, WkT);
    decoder<<<BB, 1024, 0, stream>>>(E, Ws, Wn, fc, Wog, WkT,
                                     out, out + (size_t)BB * T * NN, T);
}

// Round 12
// 2055.504 us; speedup vs baseline: 6.6188x; 6.6188x over previous
//
#include <hip/hip_runtime.h>

#define BB 256
#define NN 512
#define DD 128
#define HH 8

static constexpr float NEGC = -1e9f;
static constexpr float INV_SQRT_D = 0.08838834764831845f; // 1/sqrt(128)

__device__ __forceinline__ float dot4(float4 a, float4 b) {
    return a.x * b.x + a.y * b.y + a.z * b.z + a.w * b.w;
}
__device__ __forceinline__ void fma4(float4& a, float p, float4 e) {
    a.x += p * e.x; a.y += p * e.y; a.z += p * e.z; a.w += p * e.w;
}

// ---------------- precompute: fixed_ctx = mean_n(E) @ W_fixed ----------------
__global__ __launch_bounds__(128)
void precompute_fc(const float* __restrict__ E, const float* __restrict__ Wf,
                   float* __restrict__ fc) {
    int b = blockIdx.x, d = threadIdx.x;
    __shared__ float ge[DD];
    const float* Eb = E + (size_t)b * NN * DD;
    float s = 0.f;
    for (int n = 0; n < NN; ++n) s += Eb[n * DD + d];
    ge[d] = s * (1.0f / 512.0f);
    __syncthreads();
    float o = 0.f;
    for (int k = 0; k < DD; ++k) o += ge[k] * Wf[k * DD + d];
    fc[b * DD + d] = o;
}

// ---- precompute: WkT[k][d] = W_node[d][k] (k<128);  W_og = W_out @ Wl^T ----
__global__ __launch_bounds__(128)
void precompute_w(const float* __restrict__ Wn, const float* __restrict__ Wout,
                  float* __restrict__ Wog, float* __restrict__ WkT) {
    int k = blockIdx.x, d = threadIdx.x;
    WkT[k * DD + d] = Wn[d * 384 + k];
    float s = 0.f;
    for (int e = 0; e < DD; ++e) s += Wout[k * DD + e] * Wn[d * 384 + 256 + e];
    Wog[k * DD + d] = s;
}

// ---------------------------- main decoder ----------------------------------
// 512 threads (proven spill-free: budget 65536/512=128, live <= ~66 named
// scalars). ALL f32 (r11 lesson: fp16 anywhere in decode flips trajectories).
// E-lo f32 in LDS (q^(n&15) swizzle: volume-floor conflict-free for row AND
// column b128); E-hi from global (L2/L3). qt/P/gs via LDS broadcasts.
// Compat: 2 rows/thread (256 active) halves qt-broadcast count.
struct SMw12 {
    float EA[NN * 64];    // 131072 B  E-lo swizzled
    float Pt[NN * 8];     // 16384 B   P[n][h]; aliases: slots[4][8][128](all),
                          //           part[4][128]@0, lgp[512]@+512 floats
    float qt[HH * DD];    // 4096 B    q~ row-major; alias eb[8][128] after compat
    float qarr[DD];       // q, then g~ scratch
    float fcs[DD];
    float hcv[DD];        // heads concat
    float gs[DD];         // g~ scaled
    float curE[DD];
    float l[HH];
    float Mh[HH];
    float redf[16];
    float stat[2];
    unsigned char visf[NN];
    int   cur;
    float rbv;
};

__global__ __launch_bounds__(512)
void decoder(const float* __restrict__ E, const float* __restrict__ Ws,
             const float* __restrict__ Wn, const float* __restrict__ fc,
             const float* __restrict__ Wog, const float* __restrict__ WkT,
             float* __restrict__ out_logp, float* __restrict__ out_seq, int T) {
    __shared__ SMw12 sm;
    const int b = blockIdx.x, tid = threadIdx.x;
    const int lane = tid & 63, wv = tid >> 6;
    const int g4 = tid >> 7, d128 = tid & 127;
    const float* Eg = E + (size_t)b * NN * DD;
    const float4* Ef4 = (const float4*)Eg;

    float* const slots = &sm.Pt[0];            // [4][8][128] after P dies
    float* const part  = &sm.Pt[0];            // [4][128] small-phase partials
    float* const lgp   = &sm.Pt[512];          // [512] logits
    float* const ebp   = &sm.qt[0];            // eb[8][128] after qt dies

    // ---- init: EA (E-lo swizzled, coalesced), fcs, curE(row0), visf, rbv ----
    #pragma unroll
    for (int i = 0; i < 16; ++i) {
        int f = i * 512 + tid;
        int nn = f >> 4, cq = f & 15;
        *(float4*)&sm.EA[nn * 64 + ((cq ^ (nn & 15)) << 2)] = Ef4[nn * 32 + cq];
    }
    if (tid < DD) {
        sm.fcs[tid] = fc[b * DD + tid];
        sm.curE[tid] = Eg[tid];
    }
    sm.visf[tid] = 0;
    if (tid == 0) sm.cur = 0;
    {
        float s = 0.f;
        #pragma unroll 8
        for (int i = 0; i < 32; ++i) { float4 v = Ef4[tid * 32 + i]; s += dot4(v, v); }
        for (int o = 1; o < 64; o <<= 1) s = fmaxf(s, __shfl_xor(s, o));
        if (lane == 0) sm.redf[wv] = s;
    }
    __syncthreads();
    if (tid == 0) {
        float m = sm.redf[0];
        for (int i = 1; i < 8; ++i) m = fmaxf(m, sm.redf[i]);
        sm.rbv = sqrtf(m);
    }
    __syncthreads();

    for (int t = 0; t < T; ++t) {
        // ---- phase 0: q = fc + E[cur]@Ws + frac*Ws_last ----
        {
            float s = 0.f;
            const float* Wsg = Ws + d128;
            int k0 = g4 * 32;
            #pragma unroll 8
            for (int k = k0; k < k0 + 32; ++k) s += sm.curE[k] * Wsg[k * DD];
            if (g4 == 3) s += ((float)t / (float)T) * Wsg[DD * DD];
            part[g4 * 128 + d128] = s;
        }
        __syncthreads();                                               // B1
        if (tid < DD)
            sm.qarr[tid] = sm.fcs[tid] + part[0 * 128 + tid] + part[1 * 128 + tid]
                         + part[2 * 128 + tid] + part[3 * 128 + tid];
        __syncthreads();                                               // B2
        // ---- qt (0.25 folded) + Cauchy-Schwarz norms ----
        {
            const int hA = g4, hB = g4 + 4;
            const float* WA = WkT + (hA * 16) * DD + d128;
            const float* WB = WkT + (hB * 16) * DD + d128;
            float a = 0.f, c = 0.f;
            #pragma unroll
            for (int j = 0; j < 16; ++j) {
                a += sm.qarr[hA * 16 + j] * WA[j * DD];
                c += sm.qarr[hB * 16 + j] * WB[j * DD];
            }
            a *= 0.25f; c *= 0.25f;
            sm.qt[hA * DD + d128] = a;
            sm.qt[hB * DD + d128] = c;
            float sa = a * a, sc = c * c;
            for (int o = 1; o < 64; o <<= 1) {
                sa += __shfl_xor(sa, o);
                sc += __shfl_xor(sc, o);
            }
            if (lane == 0) { sm.redf[wv] = sa; sm.redf[8 + wv] = sc; }
        }
        __syncthreads();                                               // B3
        if (tid < 8) {
            int h = tid;
            float ss = (h < 4) ? (sm.redf[2 * h] + sm.redf[2 * h + 1])
                               : (sm.redf[8 + 2 * (h - 4)] + sm.redf[8 + 2 * (h - 4) + 1]);
            sm.Mh[h] = sqrtf(ss) * sm.rbv;
        }
        __syncthreads();                                               // B4

        // ---- compat: 2 rows/thread (tid<256), qt quads amortized over rows ----
        if (tid < 256) {
            const int n0 = tid, n1 = tid + 256;
            const int m0 = n0 & 15, m1 = n1 & 15;
            float b0 = 0.f, b1 = 0.f, b2 = 0.f, b3 = 0.f,
                  b4 = 0.f, b5 = 0.f, b6 = 0.f, b7 = 0.f;
            float c0 = 0.f, c1 = 0.f, c2 = 0.f, c3 = 0.f,
                  c4 = 0.f, c5 = 0.f, c6 = 0.f, c7 = 0.f;
            #pragma unroll 4
            for (int qd = 0; qd < 16; ++qd) {      // lo half from LDS
                float4 e0 = *(const float4*)&sm.EA[n0 * 64 + ((qd ^ m0) << 2)];
                float4 e1 = *(const float4*)&sm.EA[n1 * 64 + ((qd ^ m1) << 2)];
#define CH(h_, bb_, cc_) { float4 qv = *(const float4*)&sm.qt[h_ * DD + qd * 4]; \
                bb_ += dot4(qv, e0); cc_ += dot4(qv, e1); }
                CH(0, b0, c0) CH(1, b1, c1) CH(2, b2, c2) CH(3, b3, c3)
                CH(4, b4, c4) CH(5, b5, c5) CH(6, b6, c6) CH(7, b7, c7)
#undef CH
            }
            #pragma unroll 4
            for (int qd = 0; qd < 16; ++qd) {      // hi half from global
                float4 e0 = Ef4[n0 * 32 + 16 + qd];
                float4 e1 = Ef4[n1 * 32 + 16 + qd];
#define CH(h_, bb_, cc_) { float4 qv = *(const float4*)&sm.qt[h_ * DD + 64 + qd * 4]; \
                bb_ += dot4(qv, e0); cc_ += dot4(qv, e1); }
                CH(0, b0, c0) CH(1, b1, c1) CH(2, b2, c2) CH(3, b3, c3)
                CH(4, b4, c4) CH(5, b5, c5) CH(6, b6, c6) CH(7, b7, c7)
#undef CH
            }
            const bool v0 = (sm.visf[n0] != 0), v1 = (sm.visf[n1] != 0);
            float4 P0a, P0b, P1a, P1b;
            P0a.x = v0 ? 0.f : expf(b0 - sm.Mh[0]);
            P0a.y = v0 ? 0.f : expf(b1 - sm.Mh[1]);
            P0a.z = v0 ? 0.f : expf(b2 - sm.Mh[2]);
            P0a.w = v0 ? 0.f : expf(b3 - sm.Mh[3]);
            P0b.x = v0 ? 0.f : expf(b4 - sm.Mh[4]);
            P0b.y = v0 ? 0.f : expf(b5 - sm.Mh[5]);
            P0b.z = v0 ? 0.f : expf(b6 - sm.Mh[6]);
            P0b.w = v0 ? 0.f : expf(b7 - sm.Mh[7]);
            P1a.x = v1 ? 0.f : expf(c0 - sm.Mh[0]);
            P1a.y = v1 ? 0.f : expf(c1 - sm.Mh[1]);
            P1a.z = v1 ? 0.f : expf(c2 - sm.Mh[2]);
            P1a.w = v1 ? 0.f : expf(c3 - sm.Mh[3]);
            P1b.x = v1 ? 0.f : expf(c4 - sm.Mh[4]);
            P1b.y = v1 ? 0.f : expf(c5 - sm.Mh[5]);
            P1b.z = v1 ? 0.f : expf(c6 - sm.Mh[6]);
            P1b.w = v1 ? 0.f : expf(c7 - sm.Mh[7]);
            *(float4*)&sm.Pt[n0 * 8]     = P0a;
            *(float4*)&sm.Pt[n0 * 8 + 4] = P0b;
            *(float4*)&sm.Pt[n1 * 8]     = P1a;
            *(float4*)&sm.Pt[n1 * 8 + 4] = P1b;
        }
        __syncthreads();                                               // B5

        // ---- l[h] (wave h) + e-bar accumulate (all threads) ----
        {
            const int h = wv;
            float sl = 0.f;
            #pragma unroll
            for (int i = 0; i < 8; ++i) sl += sm.Pt[(lane + i * 64) * 8 + h];
            for (int o = 1; o < 64; o <<= 1) sl += __shfl_xor(sl, o);
            if (lane == 0) sm.l[h] = sl;
        }
        const int dq = tid & 31, ch = tid >> 5;    // d-quad, 32-row chunk
        float4 a0 = {0,0,0,0}, a1 = {0,0,0,0}, a2 = {0,0,0,0}, a3 = {0,0,0,0},
               a4 = {0,0,0,0}, a5 = {0,0,0,0}, a6 = {0,0,0,0}, a7 = {0,0,0,0};
        {
            const int r0 = ch * 32;
            #pragma unroll 2
            for (int i = 0; i < 32; ++i) {
                const int r = r0 + i;
                float4 ev = (dq < 16)
                    ? *(const float4*)&sm.EA[r * 64 + ((dq ^ (r & 15)) << 2)]
                    : Ef4[r * 32 + dq];
                float4 pA = *(const float4*)&sm.Pt[r * 8];
                float4 pB = *(const float4*)&sm.Pt[r * 8 + 4];
                fma4(a0, pA.x, ev); fma4(a1, pA.y, ev);
                fma4(a2, pA.z, ev); fma4(a3, pA.w, ev);
                fma4(a4, pB.x, ev); fma4(a5, pB.y, ev);
                fma4(a6, pB.z, ev); fma4(a7, pB.w, ev);
            }
        }
        __syncthreads();                          // B6: P dead, slots alias ok
        {   // staged partial combine: 4 rounds into 4 slots (slot = ch&3)
            const int slot = ch & 3, rnd = ch >> 2;
            #pragma unroll
            for (int rr = 0; rr < 4; ++rr) {
                if (rnd == rr) {
                    float* sp = slots + (size_t)slot * 1024 + dq * 4;
                    if (rr == 0) {
#define STW(h_, av_) *(float4*)&sp[h_ * 128] = av_;
                        STW(0, a0) STW(1, a1) STW(2, a2) STW(3, a3)
                        STW(4, a4) STW(5, a5) STW(6, a6) STW(7, a7)
#undef STW
                    } else {
#define STA(h_, av_) { float4 tv = *(float4*)&sp[h_ * 128];                  \
                        tv.x += av_.x; tv.y += av_.y; tv.z += av_.z; tv.w += av_.w; \
                        *(float4*)&sp[h_ * 128] = tv; }
                        STA(0, a0) STA(1, a1) STA(2, a2) STA(3, a3)
                        STA(4, a4) STA(5, a5) STA(6, a6) STA(7, a7)
#undef STA
                    }
                }
                __syncthreads();                                       // B7-B10
            }
        }
        {   // combine 4 slots -> eb[h][d] normalized (eb aliases qt)
            const int h = tid >> 6, d2 = (tid & 63) * 2;
            float inv = 1.0f / sm.l[h];
            #pragma unroll
            for (int r = 0; r < 2; ++r) {
                int d = d2 + r;
                float a = slots[0 * 1024 + h * 128 + d] + slots[1 * 1024 + h * 128 + d]
                        + slots[2 * 1024 + h * 128 + d] + slots[3 * 1024 + h * 128 + d];
                ebp[h * 128 + d] = a * inv;
            }
        }
        __syncthreads();                                               // B11

        // ---- hc = eb @ Wv ----
        {
            float s = 0.f;
            int k0 = g4 * 32;
            const int hh = d128 >> 4;
            const float* Wv = Wn + 128 + d128;
            #pragma unroll 8
            for (int d = k0; d < k0 + 32; ++d) s += ebp[hh * 128 + d] * Wv[d * 384];
            part[g4 * 128 + d128] = s;
        }
        __syncthreads();                                               // B12
        if (tid < DD)
            sm.hcv[tid] = part[0 * 128 + tid] + part[1 * 128 + tid]
                        + part[2 * 128 + tid] + part[3 * 128 + tid];
        __syncthreads();                                               // B13
        // ---- g~ = (hc @ Wog) * inv_sqrt_D ----
        {
            float s = 0.f;
            int k0 = g4 * 32;
            #pragma unroll 8
            for (int k = k0; k < k0 + 32; ++k) s += sm.hcv[k] * Wog[k * DD + d128];
            part[g4 * 128 + d128] = s;
        }
        __syncthreads();                                               // B14
        if (tid < DD)
            sm.gs[tid] = (part[0 * 128 + tid] + part[1 * 128 + tid]
                        + part[2 * 128 + tid] + part[3 * 128 + tid]) * INV_SQRT_D;
        __syncthreads();                                               // B15

        // ---- logits: thread n = g~ . E[n] (lo LDS, hi global) ----
        {
            const int n = tid, nm = n & 15;
            float s = 0.f;
            #pragma unroll 4
            for (int qd = 0; qd < 16; ++qd) {
                float4 gq = *(const float4*)&sm.gs[qd * 4];
                float4 ev = *(const float4*)&sm.EA[n * 64 + ((qd ^ nm) << 2)];
                s += dot4(gq, ev);
            }
            #pragma unroll 4
            for (int qd = 0; qd < 16; ++qd) {
                float4 gq = *(const float4*)&sm.gs[64 + qd * 4];
                float4 ev = Ef4[n * 32 + 16 + qd];
                s += dot4(gq, ev);
            }
            lgp[n] = sm.visf[n] ? NEGC : 10.0f * tanhf(s);
        }
        __syncthreads();                                               // B16

        // ---- stats + argmax in wave 0 (r10's passing block) ----
        if (wv == 0) {
            float x0 = lgp[lane],       x1 = lgp[lane + 64],
                  x2 = lgp[lane + 128], x3 = lgp[lane + 192],
                  x4 = lgp[lane + 256], x5 = lgp[lane + 320],
                  x6 = lgp[lane + 384], x7 = lgp[lane + 448];
            float m = fmaxf(fmaxf(fmaxf(x0, x1), fmaxf(x2, x3)),
                            fmaxf(fmaxf(x4, x5), fmaxf(x6, x7)));
            for (int o = 1; o < 64; o <<= 1) m = fmaxf(m, __shfl_xor(m, o));
            float ssum = expf(x0 - m) + expf(x1 - m) + expf(x2 - m) + expf(x3 - m)
                       + expf(x4 - m) + expf(x5 - m) + expf(x6 - m) + expf(x7 - m);
            for (int o = 1; o < 64; o <<= 1) ssum += __shfl_xor(ssum, o);
            float lse = logf(ssum);
            float bv = (x0 - m) - lse; int bi = lane;
#define AMX(xi, ii) { float v_ = ((xi) - m) - lse; int i_ = (ii);           \
            if (v_ > bv) { bv = v_; bi = i_; } }
            AMX(x1, lane + 64)  AMX(x2, lane + 128) AMX(x3, lane + 192)
            AMX(x4, lane + 256) AMX(x5, lane + 320) AMX(x6, lane + 384)
            AMX(x7, lane + 448)
#undef AMX
            for (int o = 1; o < 64; o <<= 1) {
                float ov = __shfl_xor(bv, o);
                int   oi = __shfl_xor(bi, o);
                if (ov > bv || (ov == bv && oi < bi)) { bv = ov; bi = oi; }
            }
            if (lane == 0) {
                sm.stat[0] = m;
                sm.stat[1] = lse;
                sm.cur = bi;
                out_seq[(size_t)b * T + t] = (float)bi;
            }
        }
        __syncthreads();                                               // B17
        // ---- store log_p; update visited + curE ----
        {
            float lp = (lgp[tid] - sm.stat[0]) - sm.stat[1];
            out_logp[((size_t)b * T + t) * NN + tid] = lp;
            const int cu = sm.cur;
            if (tid == cu) sm.visf[tid] = 1;
            if (tid < DD) {
                float vv;
                if (tid < 64)
                    vv = sm.EA[cu * 64 + ((((tid >> 2) ^ (cu & 15))) << 2) + (tid & 3)];
                else
                    vv = Eg[cu * DD + tid];
                sm.curE[tid] = vv;
            }
        }
        __syncthreads();                                               // B18
    }
}

// ------------------------------- launcher -----------------------------------
extern "C" void kernel_launch(void* const* d_in, const int* in_sizes, int n_in,
                              void* d_out, int out_size, void* d_ws, size_t ws_size,
                              hipStream_t stream) {
    const float* E    = (const float*)d_in[0];   // [B,N,D]
    const float* Wn   = (const float*)d_in[1];   // [D,3D]
    const float* Wf   = (const float*)d_in[2];   // [D,D]
    const float* Ws   = (const float*)d_in[3];   // [D+1,D]
    const float* Wout = (const float*)d_in[4];   // [D,D]
    float* out = (float*)d_out;

    const int T = out_size / (BB * (NN + 1));    // = num_steps (64)

    float* fcp = (float*)d_ws;                   // [B,D]
    float* Wog = fcp + BB * DD;                  // [128,128]
    float* WkT = Wog + DD * DD;                  // [128,128]

    precompute_fc<<<BB, 128, 0, stream>>>(E, Wf, fcp);
    precompute_w<<<DD, 128, 0, stream>>>(Wn, Wout, Wog, WkT);
    decoder<<<BB, 512, 0, stream>>>(E, Ws, Wn, fcp, Wog, WkT,
                                    out, out + (size_t)BB * T * NN, T);
}